// Round 21
// baseline (168.167 us; speedup 1.0000x reference)
//
#include <hip/hip_runtime.h>
#include <math.h>

#define D_MODEL 1024
#define NH 16
#define HD 64
#define SEQ 2048
#define NB 2
#define BSROWS (NB * SEQ)   // 4096
#define NT (SEQ / 64)       // 32 KV tiles

typedef __attribute__((ext_vector_type(8)))  short short8;
typedef __attribute__((ext_vector_type(4)))  float f32x4;
typedef __attribute__((ext_vector_type(16))) float f32x16;

__device__ __forceinline__ ushort bf16rne(float f) {
    union { float f; uint32_t u; } v; v.f = f;
    return (ushort)((v.u + 0x7FFFu + ((v.u >> 16) & 1u)) >> 16);
}

// hardware exp2: v_exp_f32 computes 2^x (single trans-pipe instruction)
__device__ __forceinline__ float hw_exp2(float x) {
    float r;
    asm("v_exp_f32 %0, %1" : "=v"(r) : "v"(x));
    return r;
}

// v_permlane32_swap_b32 a, b:  a -> [a.lo, b.lo], b -> [a.hi, b.hi]
__device__ __forceinline__ void permswap(uint32_t& a, uint32_t& b) {
    asm("v_permlane32_swap_b32 %0, %1" : "+v"(a), "+v"(b));
}

// async global->LDS, 16B per lane. LDS dest = wave-uniform base + lane*16.
__device__ __forceinline__ void gl_lds16(const void* g, void* l) {
    __builtin_amdgcn_global_load_lds(
        reinterpret_cast<const uint32_t __attribute__((address_space(1)))*>(
            reinterpret_cast<uintptr_t>(g)),
        reinterpret_cast<uint32_t __attribute__((address_space(3)))*>(
            reinterpret_cast<uintptr_t>(l)),
        16, 0, 0);
}

// ---------------------------------------------------------------------------
// fused fp32 -> bf16 convert: y 0..3 = Wq/Wk/Wv/Wo, y 4..7 = quarters of x
// ---------------------------------------------------------------------------
__global__ __launch_bounds__(256) void convert_all(const float* __restrict__ x,
                                                   const float* __restrict__ w0,
                                                   const float* __restrict__ w1,
                                                   const float* __restrict__ w2,
                                                   const float* __restrict__ w3,
                                                   ushort* __restrict__ xb,
                                                   ushort* __restrict__ qkv,
                                                   ushort* __restrict__ wo) {
    const int which = blockIdx.y;
    const float* src;
    ushort* dst;
    int i;
    if (which < 4) {
        src = (which == 0) ? w0 : (which == 1) ? w1 : (which == 2) ? w2 : w3;
        dst = (which < 3) ? (qkv + (size_t)which * D_MODEL * D_MODEL) : wo;
        i   = blockIdx.x * 256 + threadIdx.x;            // 131072 per weight
    } else {
        src = x;
        dst = xb;
        i   = ((which - 4) * 512 + blockIdx.x) * 256 + threadIdx.x;  // 524288
    }
    const float4 a = ((const float4*)src)[2 * i];
    const float4 b = ((const float4*)src)[2 * i + 1];
    union { ushort u[8]; uint4 v; } r;
    r.u[0] = bf16rne(a.x); r.u[1] = bf16rne(a.y); r.u[2] = bf16rne(a.z); r.u[3] = bf16rne(a.w);
    r.u[4] = bf16rne(b.x); r.u[5] = bf16rne(b.y); r.u[6] = bf16rne(b.z); r.u[7] = bf16rne(b.w);
    ((uint4*)dst)[i] = r.v;
}

// ---------------------------------------------------------------------------
// bf16 MFMA NT-GEMM (m97 structure) — unchanged (validated rounds 4-20).
// ---------------------------------------------------------------------------
template <int BN, int MODE>
__global__ __launch_bounds__(256) void gemm_mfma(const ushort* __restrict__ A,
                                                 const ushort* __restrict__ B,
                                                 const float* __restrict__ b0,
                                                 const float* __restrict__ b1,
                                                 const float* __restrict__ b2,
                                                 void* __restrict__ o0v,
                                                 void* __restrict__ o1v,
                                                 void* __restrict__ o2v) {
    constexpr int BM = 128, BK = 32;
    constexpr int WN = (BN == 128) ? 64 : 32;
    constexpr int NM = 4;
    constexpr int NN = WN / 16;

    __shared__ ushort As[BM * BK];
    __shared__ ushort Bs[BN * BK];

    const int tid = threadIdx.x;
    const int w   = tid >> 6;
    const int l   = tid & 63;
    const int i0  = blockIdx.x * BM;
    const int n0  = blockIdx.y * BN;

    const int wr = (w >> 1) * 64;
    const int wc = (w & 1) * WN;

    const int srow = l >> 2;
    const int scol = (l & 3) * 8;
    const ushort* ga = A + (size_t)(i0 + w * 32 + srow) * D_MODEL + scol;
    const ushort* gb = B + (size_t)(n0 + w * (BN / 4) + srow) * D_MODEL + scol;
    ushort* lA = &As[(w * 32) * BK];
    ushort* lB = &Bs[(w * (BN / 4)) * BK];

    f32x4 acc[NM][NN];
#pragma unroll
    for (int m = 0; m < NM; ++m)
#pragma unroll
        for (int n = 0; n < NN; ++n) acc[m][n] = (f32x4){0.f, 0.f, 0.f, 0.f};

    const int fr = l & 15;
    const int kc = (l >> 4) * 8;

    for (int k0 = 0; k0 < D_MODEL; k0 += BK) {
        __syncthreads();
        gl_lds16(ga, lA);
        gl_lds16(ga + 16 * D_MODEL, lA + 16 * BK);
        gl_lds16(gb, lB);
        if (BN == 128) gl_lds16(gb + 16 * D_MODEL, lB + 16 * BK);
        ga += BK; gb += BK;
        __syncthreads();

        short8 af[NM], bfr[NN];
#pragma unroll
        for (int m = 0; m < NM; ++m)
            af[m] = *(const short8*)&As[(wr + m * 16 + fr) * BK + kc];
#pragma unroll
        for (int n = 0; n < NN; ++n)
            bfr[n] = *(const short8*)&Bs[(wc + n * 16 + fr) * BK + kc];
#pragma unroll
        for (int m = 0; m < NM; ++m)
#pragma unroll
            for (int n = 0; n < NN; ++n)
                acc[m][n] = __builtin_amdgcn_mfma_f32_16x16x32_bf16(af[m], bfr[n], acc[m][n], 0, 0, 0);
    }

    const int rr = (l >> 4) * 4;

    if (MODE == 1) {
        float* out = (float*)o0v;
#pragma unroll
        for (int n = 0; n < NN; ++n) {
            const int j = n0 + wc + n * 16 + fr;
            const float bj = b0[j];
#pragma unroll
            for (int m = 0; m < NM; ++m) {
                const int row = i0 + wr + m * 16 + rr;
#pragma unroll
                for (int r = 0; r < 4; ++r)
                    out[(size_t)(row + r) * D_MODEL + j] = acc[m][n][r] + bj;
            }
        }
    } else {
        const int p = n0 >> 10;
        const float* bias = (p == 0) ? b0 : (p == 1) ? b1 : b2;
        // Q pre-scale folds 1/sqrt(64) AND log2(e): softmax done in base-2.
        const float scl = (p == 0) ? 0.18033688011112042f : 1.0f;
#pragma unroll
        for (int n = 0; n < NN; ++n) {
            const int j = n0 + wc + n * 16 + fr;
            const int f = j & 1023;
            const float bj = bias[f];
            const int h = f >> 6, d = f & 63;
#pragma unroll
            for (int m = 0; m < NM; ++m) {
                const int row = i0 + wr + m * 16 + rr;
                const int bb = row >> 11;
                const int s0 = row & (SEQ - 1);
                if (p < 2) {
                    ushort* dst = (ushort*)(p == 0 ? o0v : o1v);
#pragma unroll
                    for (int r = 0; r < 4; ++r)
                        dst[(((size_t)bb * NH + h) * SEQ + (s0 + r)) * HD + d] =
                            bf16rne((acc[m][n][r] + bj) * scl);
                } else {
                    ushort4 pk;
                    pk.x = bf16rne(acc[m][n][0] + bj);
                    pk.y = bf16rne(acc[m][n][1] + bj);
                    pk.z = bf16rne(acc[m][n][2] + bj);
                    pk.w = bf16rne(acc[m][n][3] + bj);
                    *(ushort4*)&((ushort*)o2v)[(((size_t)bb * NH + h) * HD + d) * SEQ + s0] = pk;
                }
            }
        }
    }
}

// ---------------------------------------------------------------------------
// Swapped-QK^T 32x32 MFMA flash attention — round-18/20 validated math.
// Round-21 delta: KV tiles processed in PAIRS (each LDS buffer holds 2 tiles,
// 64 KB total) -> one __syncthreads per 2 tiles (32 -> 16 barriers). Staging
// stays at 2-chunk granularity (write-then-reload keeps VGPR at 128).
// Compute body bit-identical (factored into a lambda).
// ---------------------------------------------------------------------------
__global__ __launch_bounds__(256) void attn_mfma11(const ushort* __restrict__ Q,
                                                   const ushort* __restrict__ K,
                                                   const ushort* __restrict__ Vt,
                                                   ushort* __restrict__ Aout) {
    __shared__ ushort KsB[2 * 8192];       // [buf][2 tiles][64 rows][64 cols]
    __shared__ ushort VtsB[2 * 8192];

    const int tid = threadIdx.x;
    const int w   = tid >> 6;
    const int l   = tid & 63;
    const int lq  = l & 31;
    const int hi  = l >> 5;
    // XCD-grouped decode: blocks with equal (b,h) differ by 32 -> same id%8.
    const int id  = blockIdx.x;
    const int qt  = id >> 5;
    const int b   = (id >> 4) & 1;
    const int h   = id & 15;
    const size_t bh = (size_t)b * NH + h;

    const ushort* Qg = Q  + (bh * SEQ + (size_t)qt * 128 + w * 32 + lq) * HD;
    const ushort* Kg = K  + bh * SEQ * HD;
    const ushort* Vg = Vt + bh * HD * SEQ;

    // Q B-fragments (loop-invariant)
    short8 qf[4];
#pragma unroll
    for (int dk = 0; dk < 4; ++dk)
        qf[dk] = *(const short8*)&Qg[dk * 16 + hi * 8];

    // staging: 2 chunks (16B) each of K and V per thread per 64-tile
    int srow[2], scol[2], ssw[2];
#pragma unroll
    for (int j = 0; j < 2; ++j) {
        const int idx = tid + j * 256;
        srow[j] = idx >> 3;
        scol[j] = (idx & 7) * 8;
        ssw[j]  = scol[j] ^ ((srow[j] & 7) << 3);
    }

    f32x16 oa0a, oa0b, oa1a, oa1b;
#pragma unroll
    for (int r = 0; r < 16; ++r) { oa0a[r] = 0.f; oa0b[r] = 0.f; oa1a[r] = 0.f; oa1b[r] = 0.f; }
    float m = -3.0e38f, lsum = 0.f;

    uint4 kreg[2], vreg[2];
    // prologue: tiles 0,1 -> buf0 slots 0,1; tile 2 -> regs
#pragma unroll
    for (int t = 0; t < 2; ++t) {
#pragma unroll
        for (int j = 0; j < 2; ++j) {
            kreg[j] = *(const uint4*)&Kg[((size_t)t * 64 + srow[j]) * HD + scol[j]];
            vreg[j] = *(const uint4*)&Vg[(size_t)srow[j] * SEQ + t * 64 + scol[j]];
        }
#pragma unroll
        for (int j = 0; j < 2; ++j) {
            *(uint4*)&KsB [t * 4096 + srow[j] * 64 + ssw[j]] = kreg[j];
            *(uint4*)&VtsB[t * 4096 + srow[j] * 64 + ssw[j]] = vreg[j];
        }
    }
#pragma unroll
    for (int j = 0; j < 2; ++j) {
        kreg[j] = *(const uint4*)&Kg[((size_t)2 * 64 + srow[j]) * HD + scol[j]];
        vreg[j] = *(const uint4*)&Vg[(size_t)srow[j] * SEQ + 2 * 64 + scol[j]];
    }
    __syncthreads();

    // one 64-row KV sub-tile: QK^T + online softmax + pack + PV (validated)
    auto subtile = [&](const ushort* Ks, const ushort* Vts) {
        f32x16 sc0, sc1;
#pragma unroll
        for (int r = 0; r < 16; ++r) { sc0[r] = 0.f; sc1[r] = 0.f; }
        const int ksw0 = (lq & 7) << 3;
        __builtin_amdgcn_s_setprio(1);
#pragma unroll
        for (int dk = 0; dk < 4; ++dk) {
            const int col = (dk * 16 + hi * 8) ^ ksw0;
            const short8 kf0 = *(const short8*)&Ks[lq * 64 + col];
            const short8 kf1 = *(const short8*)&Ks[(32 + lq) * 64 + col];
            sc0 = __builtin_amdgcn_mfma_f32_32x32x16_bf16(kf0, qf[dk], sc0, 0, 0, 0);
            sc1 = __builtin_amdgcn_mfma_f32_32x32x16_bf16(kf1, qf[dk], sc1, 0, 0, 0);
        }
        __builtin_amdgcn_s_setprio(0);

        float t0 = fmaxf(fmaxf(sc0[0], sc0[1]), fmaxf(sc0[2], sc0[3]));
        float t1 = fmaxf(fmaxf(sc0[4], sc0[5]), fmaxf(sc0[6], sc0[7]));
        float t2 = fmaxf(fmaxf(sc0[8], sc0[9]), fmaxf(sc0[10], sc0[11]));
        float t3 = fmaxf(fmaxf(sc0[12], sc0[13]), fmaxf(sc0[14], sc0[15]));
        float u0 = fmaxf(fmaxf(sc1[0], sc1[1]), fmaxf(sc1[2], sc1[3]));
        float u1 = fmaxf(fmaxf(sc1[4], sc1[5]), fmaxf(sc1[6], sc1[7]));
        float u2 = fmaxf(fmaxf(sc1[8], sc1[9]), fmaxf(sc1[10], sc1[11]));
        float u3 = fmaxf(fmaxf(sc1[12], sc1[13]), fmaxf(sc1[14], sc1[15]));
        float pm = fmaxf(fmaxf(fmaxf(t0, t1), fmaxf(t2, t3)),
                         fmaxf(fmaxf(u0, u1), fmaxf(u2, u3)));
        pm = fmaxf(pm, __shfl_xor(pm, 32));

        if (!__all(pm - m <= 11.0f)) {     // T13 defer-max
            const float mn = fmaxf(m, pm);
            const float corr = hw_exp2(m - mn);
            m = mn; lsum *= corr;
#pragma unroll
            for (int r = 0; r < 16; ++r) {
                oa0a[r] *= corr; oa0b[r] *= corr;
                oa1a[r] *= corr; oa1b[r] *= corr;
            }
        }

        float p0[16], p1[16];
#pragma unroll
        for (int r = 0; r < 16; ++r) { p0[r] = hw_exp2(sc0[r] - m); p1[r] = hw_exp2(sc1[r] - m); }
        lsum += (((p0[0] + p0[1]) + (p0[2] + p0[3])) + ((p0[4] + p0[5]) + (p0[6] + p0[7])))
              + (((p0[8] + p0[9]) + (p0[10] + p0[11])) + ((p0[12] + p0[13]) + (p0[14] + p0[15])))
              + (((p1[0] + p1[1]) + (p1[2] + p1[3])) + ((p1[4] + p1[5]) + (p1[6] + p1[7])))
              + (((p1[8] + p1[9]) + (p1[10] + p1[11])) + ((p1[12] + p1[13]) + (p1[14] + p1[15])));

        uint32_t pk0[8], pk1[8];
#pragma unroll
        for (int i = 0; i < 8; ++i) {
            asm("v_cvt_pk_bf16_f32 %0, %1, %2" : "=v"(pk0[i]) : "v"(p0[2 * i]), "v"(p0[2 * i + 1]));
            asm("v_cvt_pk_bf16_f32 %0, %1, %2" : "=v"(pk1[i]) : "v"(p1[2 * i]), "v"(p1[2 * i + 1]));
        }
        permswap(pk0[0], pk0[2]); permswap(pk0[1], pk0[3]);
        permswap(pk0[4], pk0[6]); permswap(pk0[5], pk0[7]);
        permswap(pk1[0], pk1[2]); permswap(pk1[1], pk1[3]);
        permswap(pk1[4], pk1[6]); permswap(pk1[5], pk1[7]);

        union U8 { uint32_t u[4]; short8 s; };
        U8 f00, f01, f10, f11;
        f00.u[0] = pk0[0]; f00.u[1] = pk0[1]; f00.u[2] = pk0[2]; f00.u[3] = pk0[3];
        f01.u[0] = pk0[4]; f01.u[1] = pk0[5]; f01.u[2] = pk0[6]; f01.u[3] = pk0[7];
        f10.u[0] = pk1[0]; f10.u[1] = pk1[1]; f10.u[2] = pk1[2]; f10.u[3] = pk1[3];
        f11.u[0] = pk1[4]; f11.u[1] = pk1[5]; f11.u[2] = pk1[6]; f11.u[3] = pk1[7];
        const short8 pf00 = f00.s, pf01 = f01.s, pf10 = f10.s, pf11 = f11.s;

        const int d0 = lq, d1 = 32 + lq;
        const int vsw0 = (d0 & 7) << 3;
        const int tA = hi * 8;
        const short8 vA0 = *(const short8*)&Vts[d0 * 64 + ((tA)      ^ vsw0)];
        const short8 vA1 = *(const short8*)&Vts[d1 * 64 + ((tA)      ^ vsw0)];
        const short8 vB0 = *(const short8*)&Vts[d0 * 64 + ((tA + 16) ^ vsw0)];
        const short8 vB1 = *(const short8*)&Vts[d1 * 64 + ((tA + 16) ^ vsw0)];
        const short8 wA0 = *(const short8*)&Vts[d0 * 64 + ((tA + 32) ^ vsw0)];
        const short8 wA1 = *(const short8*)&Vts[d1 * 64 + ((tA + 32) ^ vsw0)];
        const short8 wB0 = *(const short8*)&Vts[d0 * 64 + ((tA + 48) ^ vsw0)];
        const short8 wB1 = *(const short8*)&Vts[d1 * 64 + ((tA + 48) ^ vsw0)];
        __builtin_amdgcn_s_setprio(1);
        oa0a = __builtin_amdgcn_mfma_f32_32x32x16_bf16(vA0, pf00, oa0a, 0, 0, 0);
        oa1a = __builtin_amdgcn_mfma_f32_32x32x16_bf16(vA1, pf00, oa1a, 0, 0, 0);
        oa0b = __builtin_amdgcn_mfma_f32_32x32x16_bf16(vB0, pf01, oa0b, 0, 0, 0);
        oa1b = __builtin_amdgcn_mfma_f32_32x32x16_bf16(vB1, pf01, oa1b, 0, 0, 0);
        oa0a = __builtin_amdgcn_mfma_f32_32x32x16_bf16(wA0, pf10, oa0a, 0, 0, 0);
        oa1a = __builtin_amdgcn_mfma_f32_32x32x16_bf16(wA1, pf10, oa1a, 0, 0, 0);
        oa0b = __builtin_amdgcn_mfma_f32_32x32x16_bf16(wB0, pf11, oa0b, 0, 0, 0);
        oa1b = __builtin_amdgcn_mfma_f32_32x32x16_bf16(wB1, pf11, oa1b, 0, 0, 0);
        __builtin_amdgcn_s_setprio(0);
    };

    for (int pt = 0; pt < NT / 2; ++pt) {
        const ushort* KsC  = KsB  + (pt & 1) * 8192;
        const ushort* VtsC = VtsB + (pt & 1) * 8192;
        ushort* KsO  = KsB  + ((pt + 1) & 1) * 8192;
        ushort* VtsO = VtsB + ((pt + 1) & 1) * 8192;

        // write tile 2pt+2 (in regs) -> other buf slot 0; load tile 2pt+3
        if (pt < NT / 2 - 1) {
#pragma unroll
            for (int j = 0; j < 2; ++j) {
                *(uint4*)&KsO [srow[j] * 64 + ssw[j]] = kreg[j];
                *(uint4*)&VtsO[srow[j] * 64 + ssw[j]] = vreg[j];
            }
#pragma unroll
            for (int j = 0; j < 2; ++j) {
                kreg[j] = *(const uint4*)&Kg[((size_t)(2 * pt + 3) * 64 + srow[j]) * HD + scol[j]];
                vreg[j] = *(const uint4*)&Vg[(size_t)srow[j] * SEQ + (2 * pt + 3) * 64 + scol[j]];
            }
        }

        subtile(KsC, VtsC);                         // tile 2pt

        // write tile 2pt+3 -> other buf slot 1; load tile 2pt+4
        if (pt < NT / 2 - 1) {
#pragma unroll
            for (int j = 0; j < 2; ++j) {
                *(uint4*)&KsO [4096 + srow[j] * 64 + ssw[j]] = kreg[j];
                *(uint4*)&VtsO[4096 + srow[j] * 64 + ssw[j]] = vreg[j];
            }
            if (pt < NT / 2 - 2) {
#pragma unroll
                for (int j = 0; j < 2; ++j) {
                    kreg[j] = *(const uint4*)&Kg[((size_t)(2 * pt + 4) * 64 + srow[j]) * HD + scol[j]];
                    vreg[j] = *(const uint4*)&Vg[(size_t)srow[j] * SEQ + (2 * pt + 4) * 64 + scol[j]];
                }
            }
        }

        subtile(KsC + 4096, VtsC + 4096);           // tile 2pt+1

        __syncthreads();                            // one barrier per pair
    }

    // ---- epilogue: merge split accumulators, normalize, transpose, store ----
    lsum += __shfl_xor(lsum, 32);
    const float inv = 1.f / lsum;

    f32x16 oa0, oa1;
#pragma unroll
    for (int r = 0; r < 16; ++r) {
        oa0[r] = oa0a[r] + oa0b[r];
        oa1[r] = oa1a[r] + oa1b[r];
    }

    ushort* Ow = KsB + w * 2048;           // per-wave 32x64 region (K bufs done)
#pragma unroll
    for (int r = 0; r < 16; ++r) {
        const int dd = (r & 3) + 8 * (r >> 2) + 4 * hi;
        const int swq = (lq & 7) << 3;
        Ow[lq * 64 + ((dd)      ^ swq)] = bf16rne(oa0[r] * inv);
        Ow[lq * 64 + ((dd + 32) ^ swq)] = bf16rne(oa1[r] * inv);
    }
    const size_t orow0 = (size_t)b * SEQ + (size_t)qt * 128 + w * 32;
#pragma unroll
    for (int i = 0; i < 4; ++i) {
        const int row = (l >> 3) + 8 * i;
        const int d0 = (l & 7) * 8;
        const uint4 v = *(const uint4*)&Ow[row * 64 + (d0 ^ ((row & 7) << 3))];
        *(uint4*)&Aout[(orow0 + row) * D_MODEL + h * HD + d0] = v;
    }
}

// ---------------------------------------------------------------------------
extern "C" void kernel_launch(void* const* d_in, const int* in_sizes, int n_in,
                              void* d_out, int out_size, void* d_ws, size_t ws_size,
                              hipStream_t stream) {
    const float* x  = (const float*)d_in[0];
    const float* Wq = (const float*)d_in[1];
    const float* bq = (const float*)d_in[2];
    const float* Wk = (const float*)d_in[3];
    const float* bk = (const float*)d_in[4];
    const float* Wv = (const float*)d_in[5];
    const float* bv = (const float*)d_in[6];
    const float* Wo = (const float*)d_in[7];
    const float* bo = (const float*)d_in[8];
    float* out = (float*)d_out;

    ushort* xb   = (ushort*)d_ws;
    ushort* Wqkv = xb   + (size_t)BSROWS * D_MODEL;
    ushort* Wob  = Wqkv + (size_t)3 * D_MODEL * D_MODEL;
    ushort* Qw   = Wob  + (size_t)D_MODEL * D_MODEL;
    ushort* Kw   = Qw   + (size_t)BSROWS * D_MODEL;
    ushort* Vw   = Kw   + (size_t)BSROWS * D_MODEL;
    ushort* Ab   = Vw   + (size_t)BSROWS * D_MODEL;

    convert_all<<<dim3(512, 8), 256, 0, stream>>>(x, Wq, Wk, Wv, Wo, xb, Wqkv, Wob);

    gemm_mfma<128, 0><<<dim3(32, 24), 256, 0, stream>>>(
        xb, Wqkv, bq, bk, bv, Qw, Kw, Vw);

    // 1D grid, XCD-grouped: id = (b*16+h) + 32*qt
    attn_mfma11<<<dim3((SEQ / 128) * NH * NB), 256, 0, stream>>>(Qw, Kw, Vw, Ab);

    // O projection: BN=64 -> grid (32,16) = 512 blocks (2 blocks/CU)
    gemm_mfma<64, 1><<<dim3(32, 16), 256, 0, stream>>>(
        Ab, Wob, bo, nullptr, nullptr, out, nullptr, nullptr);
}

// Round 22
// 126.910 us; speedup vs baseline: 1.3251x; 1.3251x over previous
//
#include <hip/hip_runtime.h>
#include <math.h>

#define D_MODEL 1024
#define NH 16
#define HD 64
#define SEQ 2048
#define NB 2
#define BSROWS (NB * SEQ)   // 4096
#define NT (SEQ / 64)       // 32 KV tiles

typedef __attribute__((ext_vector_type(8)))  short short8;
typedef __attribute__((ext_vector_type(4)))  float f32x4;
typedef __attribute__((ext_vector_type(16))) float f32x16;

__device__ __forceinline__ ushort bf16rne(float f) {
    union { float f; uint32_t u; } v; v.f = f;
    return (ushort)((v.u + 0x7FFFu + ((v.u >> 16) & 1u)) >> 16);
}

// hardware exp2: v_exp_f32 computes 2^x (single trans-pipe instruction)
__device__ __forceinline__ float hw_exp2(float x) {
    float r;
    asm("v_exp_f32 %0, %1" : "=v"(r) : "v"(x));
    return r;
}

// v_permlane32_swap_b32 a, b:  a -> [a.lo, b.lo], b -> [a.hi, b.hi]
__device__ __forceinline__ void permswap(uint32_t& a, uint32_t& b) {
    asm("v_permlane32_swap_b32 %0, %1" : "+v"(a), "+v"(b));
}

// async global->LDS, 16B per lane. LDS dest = wave-uniform base + lane*16.
__device__ __forceinline__ void gl_lds16(const void* g, void* l) {
    __builtin_amdgcn_global_load_lds(
        reinterpret_cast<const uint32_t __attribute__((address_space(1)))*>(
            reinterpret_cast<uintptr_t>(g)),
        reinterpret_cast<uint32_t __attribute__((address_space(3)))*>(
            reinterpret_cast<uintptr_t>(l)),
        16, 0, 0);
}

// ---------------------------------------------------------------------------
// fused fp32 -> bf16 convert: y 0..3 = Wq/Wk/Wv/Wo, y 4..7 = quarters of x
// ---------------------------------------------------------------------------
__global__ __launch_bounds__(256) void convert_all(const float* __restrict__ x,
                                                   const float* __restrict__ w0,
                                                   const float* __restrict__ w1,
                                                   const float* __restrict__ w2,
                                                   const float* __restrict__ w3,
                                                   ushort* __restrict__ xb,
                                                   ushort* __restrict__ qkv,
                                                   ushort* __restrict__ wo) {
    const int which = blockIdx.y;
    const float* src;
    ushort* dst;
    int i;
    if (which < 4) {
        src = (which == 0) ? w0 : (which == 1) ? w1 : (which == 2) ? w2 : w3;
        dst = (which < 3) ? (qkv + (size_t)which * D_MODEL * D_MODEL) : wo;
        i   = blockIdx.x * 256 + threadIdx.x;            // 131072 per weight
    } else {
        src = x;
        dst = xb;
        i   = ((which - 4) * 512 + blockIdx.x) * 256 + threadIdx.x;  // 524288
    }
    const float4 a = ((const float4*)src)[2 * i];
    const float4 b = ((const float4*)src)[2 * i + 1];
    union { ushort u[8]; uint4 v; } r;
    r.u[0] = bf16rne(a.x); r.u[1] = bf16rne(a.y); r.u[2] = bf16rne(a.z); r.u[3] = bf16rne(a.w);
    r.u[4] = bf16rne(b.x); r.u[5] = bf16rne(b.y); r.u[6] = bf16rne(b.z); r.u[7] = bf16rne(b.w);
    ((uint4*)dst)[i] = r.v;
}

// ---------------------------------------------------------------------------
// bf16 MFMA NT-GEMM (m97 structure) — unchanged (validated rounds 4-20).
// ---------------------------------------------------------------------------
template <int BN, int MODE>
__global__ __launch_bounds__(256) void gemm_mfma(const ushort* __restrict__ A,
                                                 const ushort* __restrict__ B,
                                                 const float* __restrict__ b0,
                                                 const float* __restrict__ b1,
                                                 const float* __restrict__ b2,
                                                 void* __restrict__ o0v,
                                                 void* __restrict__ o1v,
                                                 void* __restrict__ o2v) {
    constexpr int BM = 128, BK = 32;
    constexpr int WN = (BN == 128) ? 64 : 32;
    constexpr int NM = 4;
    constexpr int NN = WN / 16;

    __shared__ ushort As[BM * BK];
    __shared__ ushort Bs[BN * BK];

    const int tid = threadIdx.x;
    const int w   = tid >> 6;
    const int l   = tid & 63;
    const int i0  = blockIdx.x * BM;
    const int n0  = blockIdx.y * BN;

    const int wr = (w >> 1) * 64;
    const int wc = (w & 1) * WN;

    const int srow = l >> 2;
    const int scol = (l & 3) * 8;
    const ushort* ga = A + (size_t)(i0 + w * 32 + srow) * D_MODEL + scol;
    const ushort* gb = B + (size_t)(n0 + w * (BN / 4) + srow) * D_MODEL + scol;
    ushort* lA = &As[(w * 32) * BK];
    ushort* lB = &Bs[(w * (BN / 4)) * BK];

    f32x4 acc[NM][NN];
#pragma unroll
    for (int m = 0; m < NM; ++m)
#pragma unroll
        for (int n = 0; n < NN; ++n) acc[m][n] = (f32x4){0.f, 0.f, 0.f, 0.f};

    const int fr = l & 15;
    const int kc = (l >> 4) * 8;

    for (int k0 = 0; k0 < D_MODEL; k0 += BK) {
        __syncthreads();
        gl_lds16(ga, lA);
        gl_lds16(ga + 16 * D_MODEL, lA + 16 * BK);
        gl_lds16(gb, lB);
        if (BN == 128) gl_lds16(gb + 16 * D_MODEL, lB + 16 * BK);
        ga += BK; gb += BK;
        __syncthreads();

        short8 af[NM], bfr[NN];
#pragma unroll
        for (int m = 0; m < NM; ++m)
            af[m] = *(const short8*)&As[(wr + m * 16 + fr) * BK + kc];
#pragma unroll
        for (int n = 0; n < NN; ++n)
            bfr[n] = *(const short8*)&Bs[(wc + n * 16 + fr) * BK + kc];
#pragma unroll
        for (int m = 0; m < NM; ++m)
#pragma unroll
            for (int n = 0; n < NN; ++n)
                acc[m][n] = __builtin_amdgcn_mfma_f32_16x16x32_bf16(af[m], bfr[n], acc[m][n], 0, 0, 0);
    }

    const int rr = (l >> 4) * 4;

    if (MODE == 1) {
        float* out = (float*)o0v;
#pragma unroll
        for (int n = 0; n < NN; ++n) {
            const int j = n0 + wc + n * 16 + fr;
            const float bj = b0[j];
#pragma unroll
            for (int m = 0; m < NM; ++m) {
                const int row = i0 + wr + m * 16 + rr;
#pragma unroll
                for (int r = 0; r < 4; ++r)
                    out[(size_t)(row + r) * D_MODEL + j] = acc[m][n][r] + bj;
            }
        }
    } else {
        const int p = n0 >> 10;
        const float* bias = (p == 0) ? b0 : (p == 1) ? b1 : b2;
        // Q pre-scale folds 1/sqrt(64) AND log2(e): softmax done in base-2.
        const float scl = (p == 0) ? 0.18033688011112042f : 1.0f;
#pragma unroll
        for (int n = 0; n < NN; ++n) {
            const int j = n0 + wc + n * 16 + fr;
            const int f = j & 1023;
            const float bj = bias[f];
            const int h = f >> 6, d = f & 63;
#pragma unroll
            for (int m = 0; m < NM; ++m) {
                const int row = i0 + wr + m * 16 + rr;
                const int bb = row >> 11;
                const int s0 = row & (SEQ - 1);
                if (p < 2) {
                    ushort* dst = (ushort*)(p == 0 ? o0v : o1v);
#pragma unroll
                    for (int r = 0; r < 4; ++r)
                        dst[(((size_t)bb * NH + h) * SEQ + (s0 + r)) * HD + d] =
                            bf16rne((acc[m][n][r] + bj) * scl);
                } else {
                    ushort4 pk;
                    pk.x = bf16rne(acc[m][n][0] + bj);
                    pk.y = bf16rne(acc[m][n][1] + bj);
                    pk.z = bf16rne(acc[m][n][2] + bj);
                    pk.w = bf16rne(acc[m][n][3] + bj);
                    *(ushort4*)&((ushort*)o2v)[(((size_t)bb * NH + h) * HD + d) * SEQ + s0] = pk;
                }
            }
        }
    }
}

// ---------------------------------------------------------------------------
// Swapped-QK^T 32x32 MFMA flash attention — validated best (rounds 18/20):
// PV-split ILP + XCD-grouped 1D grid + HW exp2 + permlane32_swap P-exchange.
// Structural plateau: VGPR=128, LDS=32KB, 2 blocks/CU — every attempt to add
// per-iteration state (3-buffer pipeline, paired tiles) crossed a resource
// cliff (VGPR>128 or LDS>64KB pad) and regressed 2x.
// ---------------------------------------------------------------------------
__global__ __launch_bounds__(256) void attn_mfma9(const ushort* __restrict__ Q,
                                                  const ushort* __restrict__ K,
                                                  const ushort* __restrict__ Vt,
                                                  ushort* __restrict__ Aout) {
    __shared__ ushort KsB[2 * 4096];       // [buf][64 rows][64 cols] swizzled
    __shared__ ushort VtsB[2 * 4096];

    const int tid = threadIdx.x;
    const int w   = tid >> 6;
    const int l   = tid & 63;
    const int lq  = l & 31;
    const int hi  = l >> 5;
    // XCD-grouped decode: blocks with equal (b,h) differ by 32 -> same id%8.
    const int id  = blockIdx.x;
    const int qt  = id >> 5;
    const int b   = (id >> 4) & 1;
    const int h   = id & 15;
    const size_t bh = (size_t)b * NH + h;

    const ushort* Qg = Q  + (bh * SEQ + (size_t)qt * 128 + w * 32 + lq) * HD;
    const ushort* Kg = K  + bh * SEQ * HD;
    const ushort* Vg = Vt + bh * HD * SEQ;

    // Q B-fragments (loop-invariant)
    short8 qf[4];
#pragma unroll
    for (int dk = 0; dk < 4; ++dk)
        qf[dk] = *(const short8*)&Qg[dk * 16 + hi * 8];

    // staging: 2 chunks (16B) each of K and V per thread
    int srow[2], scol[2], ssw[2];
#pragma unroll
    for (int j = 0; j < 2; ++j) {
        const int idx = tid + j * 256;
        srow[j] = idx >> 3;
        scol[j] = (idx & 7) * 8;
        ssw[j]  = scol[j] ^ ((srow[j] & 7) << 3);
    }

    uint4 kreg[2], vreg[2];
#pragma unroll
    for (int j = 0; j < 2; ++j) {          // prologue: tile 0 -> buf 0
        kreg[j] = *(const uint4*)&Kg[(size_t)srow[j] * HD + scol[j]];
        vreg[j] = *(const uint4*)&Vg[(size_t)srow[j] * SEQ + scol[j]];
    }
#pragma unroll
    for (int j = 0; j < 2; ++j) {
        *(uint4*)&KsB [srow[j] * 64 + ssw[j]] = kreg[j];
        *(uint4*)&VtsB[srow[j] * 64 + ssw[j]] = vreg[j];
    }
    __syncthreads();

    f32x16 oa0a, oa0b, oa1a, oa1b;
#pragma unroll
    for (int r = 0; r < 16; ++r) { oa0a[r] = 0.f; oa0b[r] = 0.f; oa1a[r] = 0.f; oa1b[r] = 0.f; }
    float m = -3.0e38f, lsum = 0.f;

    for (int kt = 0; kt < NT; ++kt) {
        const ushort* Ks  = &KsB [(kt & 1) * 4096];
        const ushort* Vts = &VtsB[(kt & 1) * 4096];
        ushort* Ksn  = &KsB [((kt + 1) & 1) * 4096];
        ushort* Vtsn = &VtsB[((kt + 1) & 1) * 4096];

        // T14: issue next tile's global loads first (latency hides under compute)
        if (kt + 1 < NT) {
#pragma unroll
            for (int j = 0; j < 2; ++j) {
                kreg[j] = *(const uint4*)&Kg[((size_t)(kt + 1) * 64 + srow[j]) * HD + scol[j]];
                vreg[j] = *(const uint4*)&Vg[(size_t)srow[j] * SEQ + (kt + 1) * 64 + scol[j]];
            }
        }

        // ---- QK^T: two independent chains, interleaved ----
        f32x16 sc0, sc1;
#pragma unroll
        for (int r = 0; r < 16; ++r) { sc0[r] = 0.f; sc1[r] = 0.f; }
        const int ksw0 = (lq & 7) << 3;
        __builtin_amdgcn_s_setprio(1);
#pragma unroll
        for (int dk = 0; dk < 4; ++dk) {
            const int col = (dk * 16 + hi * 8) ^ ksw0;
            const short8 kf0 = *(const short8*)&Ks[lq * 64 + col];
            const short8 kf1 = *(const short8*)&Ks[(32 + lq) * 64 + col];
            sc0 = __builtin_amdgcn_mfma_f32_32x32x16_bf16(kf0, qf[dk], sc0, 0, 0, 0);
            sc1 = __builtin_amdgcn_mfma_f32_32x32x16_bf16(kf1, qf[dk], sc1, 0, 0, 0);
        }
        __builtin_amdgcn_s_setprio(0);

        // ---- softmax over all 32 scores (base-2 domain, HW exp2) ----
        float t0 = fmaxf(fmaxf(sc0[0], sc0[1]), fmaxf(sc0[2], sc0[3]));
        float t1 = fmaxf(fmaxf(sc0[4], sc0[5]), fmaxf(sc0[6], sc0[7]));
        float t2 = fmaxf(fmaxf(sc0[8], sc0[9]), fmaxf(sc0[10], sc0[11]));
        float t3 = fmaxf(fmaxf(sc0[12], sc0[13]), fmaxf(sc0[14], sc0[15]));
        float u0 = fmaxf(fmaxf(sc1[0], sc1[1]), fmaxf(sc1[2], sc1[3]));
        float u1 = fmaxf(fmaxf(sc1[4], sc1[5]), fmaxf(sc1[6], sc1[7]));
        float u2 = fmaxf(fmaxf(sc1[8], sc1[9]), fmaxf(sc1[10], sc1[11]));
        float u3 = fmaxf(fmaxf(sc1[12], sc1[13]), fmaxf(sc1[14], sc1[15]));
        float pm = fmaxf(fmaxf(fmaxf(t0, t1), fmaxf(t2, t3)),
                         fmaxf(fmaxf(u0, u1), fmaxf(u2, u3)));
        pm = fmaxf(pm, __shfl_xor(pm, 32));

        if (!__all(pm - m <= 11.0f)) {     // T13 defer-max (2^11 ~ e^7.6 bound)
            const float mn = fmaxf(m, pm);
            const float corr = hw_exp2(m - mn);
            m = mn; lsum *= corr;
#pragma unroll
            for (int r = 0; r < 16; ++r) {
                oa0a[r] *= corr; oa0b[r] *= corr;
                oa1a[r] *= corr; oa1b[r] *= corr;
            }
        }

        float p0[16], p1[16];
#pragma unroll
        for (int r = 0; r < 16; ++r) { p0[r] = hw_exp2(sc0[r] - m); p1[r] = hw_exp2(sc1[r] - m); }
        lsum += (((p0[0] + p0[1]) + (p0[2] + p0[3])) + ((p0[4] + p0[5]) + (p0[6] + p0[7])))
              + (((p0[8] + p0[9]) + (p0[10] + p0[11])) + ((p0[12] + p0[13]) + (p0[14] + p0[15])))
              + (((p1[0] + p1[1]) + (p1[2] + p1[3])) + ((p1[4] + p1[5]) + (p1[6] + p1[7])))
              + (((p1[8] + p1[9]) + (p1[10] + p1[11])) + ((p1[12] + p1[13]) + (p1[14] + p1[15])));

        // ---- pack P -> bf16; half-exchange via v_permlane32_swap_b32 ----
        uint32_t pk0[8], pk1[8];
#pragma unroll
        for (int i = 0; i < 8; ++i) {
            asm("v_cvt_pk_bf16_f32 %0, %1, %2" : "=v"(pk0[i]) : "v"(p0[2 * i]), "v"(p0[2 * i + 1]));
            asm("v_cvt_pk_bf16_f32 %0, %1, %2" : "=v"(pk1[i]) : "v"(p1[2 * i]), "v"(p1[2 * i + 1]));
        }
        // swap(a,b): a=[a.lo,b.lo] b=[a.hi,b.hi] — exactly the old hi?:select
        permswap(pk0[0], pk0[2]); permswap(pk0[1], pk0[3]);
        permswap(pk0[4], pk0[6]); permswap(pk0[5], pk0[7]);
        permswap(pk1[0], pk1[2]); permswap(pk1[1], pk1[3]);
        permswap(pk1[4], pk1[6]); permswap(pk1[5], pk1[7]);

        union U8 { uint32_t u[4]; short8 s; };
        U8 f00, f01, f10, f11;
        f00.u[0] = pk0[0]; f00.u[1] = pk0[1]; f00.u[2] = pk0[2]; f00.u[3] = pk0[3];
        f01.u[0] = pk0[4]; f01.u[1] = pk0[5]; f01.u[2] = pk0[6]; f01.u[3] = pk0[7];
        f10.u[0] = pk1[0]; f10.u[1] = pk1[1]; f10.u[2] = pk1[2]; f10.u[3] = pk1[3];
        f11.u[0] = pk1[4]; f11.u[1] = pk1[5]; f11.u[2] = pk1[6]; f11.u[3] = pk1[7];
        const short8 pf00 = f00.s, pf01 = f01.s, pf10 = f10.s, pf11 = f11.s;

        // ---- PV: four 2-deep accumulator chains (split ILP) ----
        const int d0 = lq, d1 = 32 + lq;
        const int vsw0 = (d0 & 7) << 3;
        const int tA = hi * 8;
        const short8 vA0 = *(const short8*)&Vts[d0 * 64 + ((tA)      ^ vsw0)];
        const short8 vA1 = *(const short8*)&Vts[d1 * 64 + ((tA)      ^ vsw0)];
        const short8 vB0 = *(const short8*)&Vts[d0 * 64 + ((tA + 16) ^ vsw0)];
        const short8 vB1 = *(const short8*)&Vts[d1 * 64 + ((tA + 16) ^ vsw0)];
        const short8 wA0 = *(const short8*)&Vts[d0 * 64 + ((tA + 32) ^ vsw0)];
        const short8 wA1 = *(const short8*)&Vts[d1 * 64 + ((tA + 32) ^ vsw0)];
        const short8 wB0 = *(const short8*)&Vts[d0 * 64 + ((tA + 48) ^ vsw0)];
        const short8 wB1 = *(const short8*)&Vts[d1 * 64 + ((tA + 48) ^ vsw0)];
        __builtin_amdgcn_s_setprio(1);
        oa0a = __builtin_amdgcn_mfma_f32_32x32x16_bf16(vA0, pf00, oa0a, 0, 0, 0);
        oa1a = __builtin_amdgcn_mfma_f32_32x32x16_bf16(vA1, pf00, oa1a, 0, 0, 0);
        oa0b = __builtin_amdgcn_mfma_f32_32x32x16_bf16(vB0, pf01, oa0b, 0, 0, 0);
        oa1b = __builtin_amdgcn_mfma_f32_32x32x16_bf16(vB1, pf01, oa1b, 0, 0, 0);
        oa0a = __builtin_amdgcn_mfma_f32_32x32x16_bf16(wA0, pf10, oa0a, 0, 0, 0);
        oa1a = __builtin_amdgcn_mfma_f32_32x32x16_bf16(wA1, pf10, oa1a, 0, 0, 0);
        oa0b = __builtin_amdgcn_mfma_f32_32x32x16_bf16(wB0, pf11, oa0b, 0, 0, 0);
        oa1b = __builtin_amdgcn_mfma_f32_32x32x16_bf16(wB1, pf11, oa1b, 0, 0, 0);
        __builtin_amdgcn_s_setprio(0);

        // ---- write prefetched tile -> other buffer; single barrier ----
        if (kt + 1 < NT) {
#pragma unroll
            for (int j = 0; j < 2; ++j) {
                *(uint4*)&Ksn [srow[j] * 64 + ssw[j]] = kreg[j];
                *(uint4*)&Vtsn[srow[j] * 64 + ssw[j]] = vreg[j];
            }
        }
        __syncthreads();
    }

    // ---- epilogue: merge split accumulators, normalize, transpose, store ----
    lsum += __shfl_xor(lsum, 32);
    const float inv = 1.f / lsum;

    f32x16 oa0, oa1;
#pragma unroll
    for (int r = 0; r < 16; ++r) {
        oa0[r] = oa0a[r] + oa0b[r];
        oa1[r] = oa1a[r] + oa1b[r];
    }

    ushort* Ow = KsB + w * 2048;           // per-wave 32x64 region (K bufs done)
#pragma unroll
    for (int r = 0; r < 16; ++r) {
        const int dd = (r & 3) + 8 * (r >> 2) + 4 * hi;
        const int swq = (lq & 7) << 3;
        Ow[lq * 64 + ((dd)      ^ swq)] = bf16rne(oa0[r] * inv);
        Ow[lq * 64 + ((dd + 32) ^ swq)] = bf16rne(oa1[r] * inv);
    }
    const size_t orow0 = (size_t)b * SEQ + (size_t)qt * 128 + w * 32;
#pragma unroll
    for (int i = 0; i < 4; ++i) {
        const int row = (l >> 3) + 8 * i;
        const int d0 = (l & 7) * 8;
        const uint4 v = *(const uint4*)&Ow[row * 64 + (d0 ^ ((row & 7) << 3))];
        *(uint4*)&Aout[(orow0 + row) * D_MODEL + h * HD + d0] = v;
    }
}

// ---------------------------------------------------------------------------
extern "C" void kernel_launch(void* const* d_in, const int* in_sizes, int n_in,
                              void* d_out, int out_size, void* d_ws, size_t ws_size,
                              hipStream_t stream) {
    const float* x  = (const float*)d_in[0];
    const float* Wq = (const float*)d_in[1];
    const float* bq = (const float*)d_in[2];
    const float* Wk = (const float*)d_in[3];
    const float* bk = (const float*)d_in[4];
    const float* Wv = (const float*)d_in[5];
    const float* bv = (const float*)d_in[6];
    const float* Wo = (const float*)d_in[7];
    const float* bo = (const float*)d_in[8];
    float* out = (float*)d_out;

    ushort* xb   = (ushort*)d_ws;
    ushort* Wqkv = xb   + (size_t)BSROWS * D_MODEL;
    ushort* Wob  = Wqkv + (size_t)3 * D_MODEL * D_MODEL;
    ushort* Qw   = Wob  + (size_t)D_MODEL * D_MODEL;
    ushort* Kw   = Qw   + (size_t)BSROWS * D_MODEL;
    ushort* Vw   = Kw   + (size_t)BSROWS * D_MODEL;
    ushort* Ab   = Vw   + (size_t)BSROWS * D_MODEL;

    convert_all<<<dim3(512, 8), 256, 0, stream>>>(x, Wq, Wk, Wv, Wo, xb, Wqkv, Wob);

    gemm_mfma<128, 0><<<dim3(32, 24), 256, 0, stream>>>(
        xb, Wqkv, bq, bk, bv, Qw, Kw, Vw);

    // 1D grid, XCD-grouped: id = (b*16+h) + 32*qt
    attn_mfma9<<<dim3((SEQ / 128) * NH * NB), 256, 0, stream>>>(Qw, Kw, Vw, Ab);

    // O projection: BN=64 -> grid (32,16) = 512 blocks (2 blocks/CU)
    gemm_mfma<64, 1><<<dim3(32, 16), 256, 0, stream>>>(
        Ab, Wob, bo, nullptr, nullptr, out, nullptr, nullptr);
}